// Round 3
// baseline (500.900 us; speedup 1.0000x reference)
//
#include <hip/hip_runtime.h>

#define HEADS 4
#define OUTC 64
#define INC 128
#define HC 256   // HEADS*OUTC
#define NEG 0.2f

// ---- edge-layout detection: flags[0]=1 if edge_index is int64-storage ----
__global__ void k_detect(const int* __restrict__ ei, int* __restrict__ flags){
  __shared__ int cnt;
  if (threadIdx.x == 0) cnt = 0;
  __syncthreads();
  int c = 0;
  for (int i = threadIdx.x; i < 2048; i += 256){
    if (ei[2 * i + 1] == 0) c++;               // int64 high words are all 0
  }
  atomicAdd(&cnt, c);
  __syncthreads();
  if (threadIdx.x == 0) flags[0] = (cnt > 1900) ? 1 : 0;
}

// ---- canonicalize edge_index -> int32 src/dst rows ----
__global__ void k_conv_e(const int* __restrict__ ei, const int* __restrict__ flags,
                         int* __restrict__ srcc, int* __restrict__ dstc, int E){
  int e = blockIdx.x * 256 + threadIdx.x;
  if (e < E){
    if (flags[0]){ srcc[e] = ei[2 * e]; dstc[e] = ei[2 * E + 2 * e]; }
    else         { srcc[e] = ei[e];     dstc[e] = ei[E + e]; }
  }
}

// ---- GEMM (VALU, fp32): XP[N,256] = X[N,128] @ W[128,256] ----
// Block: 256 threads, 16 node-rows staged in LDS; thread t owns output column t.
__global__ __launch_bounds__(256) void k_gemm_valu(const float* __restrict__ X,
                                                   const float* __restrict__ W,
                                                   float* __restrict__ XP){
  __shared__ float xs[16][128];
  int t = threadIdx.x;
  int base = blockIdx.x * 16;
  for (int i = t; i < 16 * 128; i += 256){
    xs[i >> 7][i & 127] = X[(size_t)(base + (i >> 7)) * INC + (i & 127)];
  }
  __syncthreads();
  float acc[16];
  #pragma unroll
  for (int r = 0; r < 16; ++r) acc[r] = 0.f;
  for (int kb = 0; kb < 32; ++kb){           // K = 32 * 4
    float w0 = W[(kb * 4 + 0) * HC + t];
    float w1 = W[(kb * 4 + 1) * HC + t];
    float w2 = W[(kb * 4 + 2) * HC + t];
    float w3 = W[(kb * 4 + 3) * HC + t];
    #pragma unroll
    for (int r = 0; r < 16; ++r){
      float4 xv = *(const float4*)&xs[r][kb * 4];
      acc[r] = fmaf(xv.x, w0, acc[r]);
      acc[r] = fmaf(xv.y, w1, acc[r]);
      acc[r] = fmaf(xv.z, w2, acc[r]);
      acc[r] = fmaf(xv.w, w3, acc[r]);
    }
  }
  #pragma unroll
  for (int r = 0; r < 16; ++r){
    XP[(size_t)(base + r) * HC + t] = acc[r];
  }
}

// ---- per-(n,h) attention logits ----
__global__ __launch_bounds__(256) void k_att(const float* __restrict__ XP,
    const float* __restrict__ att_src, const float* __restrict__ att_dst,
    float* __restrict__ a_src, float* __restrict__ a_dst){
  int n = blockIdx.x;
  int h = threadIdx.x >> 6, c = threadIdx.x & 63;
  float v  = XP[(size_t)n * HC + h * OUTC + c];
  float ps = v * att_src[h * OUTC + c];
  float pd = v * att_dst[h * OUTC + c];
  #pragma unroll
  for (int m = 32; m; m >>= 1){
    ps += __shfl_xor(ps, m, 64);
    pd += __shfl_xor(pd, m, 64);
  }
  if (c == 0){ a_src[n * HEADS + h] = ps; a_dst[n * HEADS + h] = pd; }
}

// ---- degree histogram over dst ----
__global__ void k_hist(const int* __restrict__ dst, int* __restrict__ deg, int E){
  int e = blockIdx.x * 256 + threadIdx.x;
  if (e < E) atomicAdd(&deg[dst[e]], 1);
}

// ---- exclusive scan (3-phase), 1024 elems/block ----
__global__ __launch_bounds__(256) void k_scan1(const int* __restrict__ deg,
                                               int* __restrict__ out,
                                               int* __restrict__ bsum, int N){
  __shared__ int tsum[256];
  int t = threadIdx.x;
  int base = blockIdx.x * 1024 + t * 4;
  int v[4]; int s = 0;
  #pragma unroll
  for (int k = 0; k < 4; ++k){ int i = base + k; v[k] = (i < N) ? deg[i] : 0; s += v[k]; }
  tsum[t] = s;
  __syncthreads();
  for (int off = 1; off < 256; off <<= 1){
    int x = (t >= off) ? tsum[t - off] : 0;
    __syncthreads();
    tsum[t] += x;
    __syncthreads();
  }
  int excl = tsum[t] - s;
  if (t == 255) bsum[blockIdx.x] = tsum[255];
  int run = excl;
  #pragma unroll
  for (int k = 0; k < 4; ++k){ int i = base + k; if (i < N) out[i] = run; run += v[k]; }
}
__global__ void k_scan2(int* __restrict__ bsum, int nb, int* __restrict__ rowstart, int N){
  if (threadIdx.x == 0){
    int run = 0;
    for (int i = 0; i < nb; ++i){ int v = bsum[i]; bsum[i] = run; run += v; }
    rowstart[N] = run;
  }
}
__global__ __launch_bounds__(256) void k_scan3(int* __restrict__ rowstart,
                                               const int* __restrict__ bsum, int N){
  int off = bsum[blockIdx.x];
  int base = blockIdx.x * 1024 + threadIdx.x * 4;
  #pragma unroll
  for (int k = 0; k < 4; ++k){ int i = base + k; if (i < N) rowstart[i] += off; }
}

// ---- scatter edges into CSR buckets ----
__global__ void k_scatter(const int* __restrict__ src, const int* __restrict__ dst,
                          const int* __restrict__ rowstart, int* __restrict__ cursor,
                          int* __restrict__ csr, int E){
  int e = blockIdx.x * 256 + threadIdx.x;
  if (e < E){
    int d = dst[e];
    int pos = rowstart[d] + atomicAdd(&cursor[d], 1);
    csr[pos] = src[e];
  }
}

// ---- main: one wave per (node, head): online softmax + weighted gather ----
__global__ __launch_bounds__(256) void k_main(const float* __restrict__ XP,
    const float* __restrict__ a_src, const float* __restrict__ a_dst,
    const int* __restrict__ rowstart, const int* __restrict__ csr,
    const float* __restrict__ bias, float* __restrict__ out){
  int i = blockIdx.x;
  int h = threadIdx.x >> 6, lane = threadIdx.x & 63;
  int r0 = rowstart[i], r1 = rowstart[i + 1];
  int deg = r1 - r0;
  int total = deg + 1;                       // + self loop
  float adsti = a_dst[i * HEADS + h];

  // pass 1: per-lane online (m, s), then wave-combine
  float m = -1e30f, s = 0.f;
  for (int e = lane; e < total; e += 64){
    int j = (e < deg) ? csr[r0 + e] : i;
    float a = a_src[j * HEADS + h] + adsti;
    a = (a > 0.f) ? a : NEG * a;
    if (a > m){ s = s * __expf(m - a) + 1.f; m = a; }
    else        s += __expf(a - m);
  }
  #pragma unroll
  for (int msk = 32; msk; msk >>= 1){
    float m2 = __shfl_xor(m, msk, 64);
    float s2 = __shfl_xor(s, msk, 64);
    float M = fmaxf(m, m2);
    float ns = 0.f;
    if (m  > -1e29f) ns += s  * __expf(m  - M);
    if (m2 > -1e29f) ns += s2 * __expf(m2 - M);
    m = M; s = ns;
  }
  float inv_s = 1.f / s;

  // pass 2: all lanes walk the edge list; lane = channel
  float acc = 0.f;
  const float* xph = XP + h * OUTC + lane;
  for (int e = 0; e < total; ++e){
    int j = (e < deg) ? csr[r0 + e] : i;
    float a = a_src[j * HEADS + h] + adsti;
    a = (a > 0.f) ? a : NEG * a;
    float coef = __expf(a - m) * inv_s;
    acc += coef * xph[(size_t)j * HC];
  }
  out[(size_t)i * HC + h * OUTC + lane] = acc + bias[h * OUTC + lane];
}

extern "C" void kernel_launch(void* const* d_in, const int* in_sizes, int n_in,
                              void* d_out, int out_size, void* d_ws, size_t ws_size,
                              hipStream_t stream){
  const float* x       = (const float*)d_in[0];
  const float* W       = (const float*)d_in[1];
  const float* att_src = (const float*)d_in[2];
  const float* att_dst = (const float*)d_in[3];
  const float* bias    = (const float*)d_in[4];
  const int*   ei      = (const int*)d_in[5];
  int N = in_sizes[0] / INC;     // 50000
  int E = in_sizes[5] / 2;       // 800000

  char* p = (char*)d_ws;
  auto alloc = [&](size_t bytes)->char*{
    char* r = p; p += (bytes + 255) & ~(size_t)255; return r;
  };
  float* XP           = (float*)alloc((size_t)N * HC * 4);
  float* aSrc         = (float*)alloc((size_t)N * HEADS * 4);
  float* aDst         = (float*)alloc((size_t)N * HEADS * 4);
  int* deg            = (int*)alloc((size_t)N * 4);
  int* cursor         = (int*)alloc((size_t)N * 4);
  int* rowstart       = (int*)alloc(((size_t)N + 1) * 4);
  int* srcc           = (int*)alloc((size_t)E * 4);
  int* dstc           = (int*)alloc((size_t)E * 4);
  int* csr            = (int*)alloc((size_t)E * 4);
  int* bsum           = (int*)alloc(256 * 4);
  int* flags          = (int*)alloc(16);

  k_detect<<<1, 256, 0, stream>>>(ei, flags);
  k_conv_e<<<(E + 255) / 256, 256, 0, stream>>>(ei, flags, srcc, dstc, E);

  k_gemm_valu<<<N / 16, 256, 0, stream>>>(x, W, XP);
  k_att<<<N, 256, 0, stream>>>(XP, att_src, att_dst, aSrc, aDst);

  hipMemsetAsync(deg, 0, (size_t)N * 4, stream);
  hipMemsetAsync(cursor, 0, (size_t)N * 4, stream);
  k_hist<<<(E + 255) / 256, 256, 0, stream>>>(dstc, deg, E);
  int nb = (N + 1023) / 1024;
  k_scan1<<<nb, 256, 0, stream>>>(deg, rowstart, bsum, N);
  k_scan2<<<1, 64, 0, stream>>>(bsum, nb, rowstart, N);
  k_scan3<<<nb, 256, 0, stream>>>(rowstart, bsum, N);
  k_scatter<<<(E + 255) / 256, 256, 0, stream>>>(srcc, dstc, rowstart, cursor, csr, E);

  k_main<<<N, 256, 0, stream>>>(XP, aSrc, aDst, rowstart, csr, bias,
                                (float*)d_out);
}

// Round 4
// 479.701 us; speedup vs baseline: 1.0442x; 1.0442x over previous
//
#include <hip/hip_runtime.h>

#define HEADS 4
#define OUTC 64
#define INC 128
#define HC 256   // HEADS*OUTC
#define NEG 0.2f

typedef __attribute__((ext_vector_type(8))) short bf16x8;
typedef __attribute__((ext_vector_type(4))) float f32x4;

static __device__ __forceinline__ float bf2f(unsigned short u){
  unsigned int x = ((unsigned int)u) << 16;
  return __uint_as_float(x);
}
static __device__ __forceinline__ unsigned short f2bf(float f){
  unsigned int x = __float_as_uint(f);
  unsigned int lsb = (x >> 16) & 1u;
  x += 0x7fffu + lsb;           // RNE
  return (unsigned short)(x >> 16);
}

// ---- edge-layout detection: flags[0]=1 if edge_index is int64-storage ----
__global__ void k_detect(const int* __restrict__ ei, int* __restrict__ flags){
  __shared__ int cnt;
  if (threadIdx.x == 0) cnt = 0;
  __syncthreads();
  int c = 0;
  for (int i = threadIdx.x; i < 2048; i += 256){
    if (ei[2 * i + 1] == 0) c++;
  }
  atomicAdd(&cnt, c);
  __syncthreads();
  if (threadIdx.x == 0) flags[0] = (cnt > 1900) ? 1 : 0;
}

__global__ void k_conv_e(const int* __restrict__ ei, const int* __restrict__ flags,
                         int* __restrict__ srcc, int* __restrict__ dstc, int E){
  int e = blockIdx.x * 256 + threadIdx.x;
  if (e < E){
    if (flags[0]){ srcc[e] = ei[2 * e]; dstc[e] = ei[2 * E + 2 * e]; }
    else         { srcc[e] = ei[e];     dstc[e] = ei[E + e]; }
  }
}

// ---- split fp32 x into bf16 hi/lo ----
__global__ void k_split_x(const float* __restrict__ X, unsigned short* __restrict__ Xhi,
                          unsigned short* __restrict__ Xlo, int n){
  int i = blockIdx.x * 256 + threadIdx.x;
  if (i < n){
    float v = X[i];
    unsigned short hi = f2bf(v);
    Xhi[i] = hi;
    Xlo[i] = f2bf(v - bf2f(hi));
  }
}

// ---- split + transpose W: Wt*[n*128+k] from W[k*256+n] ----
__global__ void k_split_w(const float* __restrict__ W, unsigned short* __restrict__ Wthi,
                          unsigned short* __restrict__ Wtlo){
  int t = blockIdx.x * 256 + threadIdx.x;      // 0..32767
  int k = t >> 8, n = t & 255;
  float v = W[t];
  unsigned short hi = f2bf(v);
  Wthi[n * INC + k] = hi;
  Wtlo[n * INC + k] = f2bf(v - bf2f(hi));
}

// ---- MFMA GEMM (split bf16 ~= fp32): XPh[N,256] (bf16) = X @ W ----
// grid (N/16, 4); block 256 = 4 waves; wave w: cols by*64 + w*16, rows bx*16.
__global__ __launch_bounds__(256) void k_gemm(const unsigned short* __restrict__ Xhi,
    const unsigned short* __restrict__ Xlo, const unsigned short* __restrict__ Wthi,
    const unsigned short* __restrict__ Wtlo, unsigned short* __restrict__ XPh){
  int w = threadIdx.x >> 6, lane = threadIdx.x & 63;
  int m0 = blockIdx.x * 16;
  int colg = blockIdx.y * 64 + w * 16 + (lane & 15);
  int quad = lane >> 4;
  int row  = m0 + (lane & 15);
  size_t aoff = (size_t)row  * INC + quad * 8;
  size_t boff = (size_t)colg * INC + quad * 8;
  f32x4 acc = {0.f, 0.f, 0.f, 0.f};
  #pragma unroll
  for (int kk = 0; kk < 4; ++kk){              // K = 4*32; step stride 32 shorts
    bf16x8 ah = *(const bf16x8*)(Xhi  + aoff + kk * 32);
    bf16x8 al = *(const bf16x8*)(Xlo  + aoff + kk * 32);
    bf16x8 bh = *(const bf16x8*)(Wthi + boff + kk * 32);
    bf16x8 bl = *(const bf16x8*)(Wtlo + boff + kk * 32);
    acc = __builtin_amdgcn_mfma_f32_16x16x32_bf16(ah, bh, acc, 0, 0, 0);
    acc = __builtin_amdgcn_mfma_f32_16x16x32_bf16(ah, bl, acc, 0, 0, 0);
    acc = __builtin_amdgcn_mfma_f32_16x16x32_bf16(al, bh, acc, 0, 0, 0);
  }
  #pragma unroll
  for (int r = 0; r < 4; ++r){                 // C/D: col=lane&15, row=quad*4+r
    XPh[(size_t)(m0 + quad * 4 + r) * HC + colg] = f2bf(acc[r]);
  }
}

// ---- logits: wave = one node; lane covers 4 channels of head lane>>4 ----
__global__ __launch_bounds__(256) void k_att(const unsigned short* __restrict__ XPh,
    const float* __restrict__ att_src, const float* __restrict__ att_dst,
    float* __restrict__ a_src, float* __restrict__ a_dst, int N){
  int w = threadIdx.x >> 6, lane = threadIdx.x & 63;
  int n = blockIdx.x * 4 + w;
  if (n >= N) return;
  int h = lane >> 4, cg = (lane & 15) * 4;
  ushort4 uv = *(const ushort4*)&XPh[(size_t)n * HC + lane * 4];
  float4 as4 = *(const float4*)&att_src[h * OUTC + cg];
  float4 ad4 = *(const float4*)&att_dst[h * OUTC + cg];
  float x0 = bf2f(uv.x), x1 = bf2f(uv.y), x2 = bf2f(uv.z), x3 = bf2f(uv.w);
  float ps = x0 * as4.x + x1 * as4.y + x2 * as4.z + x3 * as4.w;
  float pd = x0 * ad4.x + x1 * ad4.y + x2 * ad4.z + x3 * ad4.w;
  #pragma unroll
  for (int m = 1; m < 16; m <<= 1){
    ps += __shfl_xor(ps, m, 64);
    pd += __shfl_xor(pd, m, 64);
  }
  if ((lane & 15) == 0){
    a_src[n * HEADS + h] = ps;
    a_dst[n * HEADS + h] = pd;
  }
}

// ---- degree histogram ----
__global__ void k_hist(const int* __restrict__ dst, int* __restrict__ deg, int E){
  int e = blockIdx.x * 256 + threadIdx.x;
  if (e < E) atomicAdd(&deg[dst[e]], 1);
}

// ---- exclusive scan ----
__global__ __launch_bounds__(256) void k_scan1(const int* __restrict__ deg,
                                               int* __restrict__ out,
                                               int* __restrict__ bsum, int N){
  __shared__ int tsum[256];
  int t = threadIdx.x;
  int base = blockIdx.x * 1024 + t * 4;
  int v[4]; int s = 0;
  #pragma unroll
  for (int k = 0; k < 4; ++k){ int i = base + k; v[k] = (i < N) ? deg[i] : 0; s += v[k]; }
  tsum[t] = s;
  __syncthreads();
  for (int off = 1; off < 256; off <<= 1){
    int x = (t >= off) ? tsum[t - off] : 0;
    __syncthreads();
    tsum[t] += x;
    __syncthreads();
  }
  int excl = tsum[t] - s;
  if (t == 255) bsum[blockIdx.x] = tsum[255];
  int run = excl;
  #pragma unroll
  for (int k = 0; k < 4; ++k){ int i = base + k; if (i < N) out[i] = run; run += v[k]; }
}
__global__ void k_scan2(int* __restrict__ bsum, int nb, int* __restrict__ rowstart, int N){
  if (threadIdx.x == 0){
    int run = 0;
    for (int i = 0; i < nb; ++i){ int v = bsum[i]; bsum[i] = run; run += v; }
    rowstart[N] = run;
  }
}
__global__ __launch_bounds__(256) void k_scan3(int* __restrict__ rowstart,
                                               const int* __restrict__ bsum, int N){
  int off = bsum[blockIdx.x];
  int base = blockIdx.x * 1024 + threadIdx.x * 4;
  #pragma unroll
  for (int k = 0; k < 4; ++k){ int i = base + k; if (i < N) rowstart[i] += off; }
}

__global__ void k_scatter(const int* __restrict__ src, const int* __restrict__ dst,
                          const int* __restrict__ rowstart, int* __restrict__ cursor,
                          int* __restrict__ csr, int E){
  int e = blockIdx.x * 256 + threadIdx.x;
  if (e < E){
    int d = dst[e];
    int pos = rowstart[d] + atomicAdd(&cursor[d], 1);
    csr[pos] = src[e];
  }
}

// ---- main: wave per (node, head). Fast path deg<=63: lane-parallel softmax,
// readlane-broadcast serial gather. bf16 XP gather. ----
__global__ __launch_bounds__(256) void k_main(const unsigned short* __restrict__ XPh,
    const float* __restrict__ a_src, const float* __restrict__ a_dst,
    const int* __restrict__ rowstart, const int* __restrict__ csr,
    const float* __restrict__ bias, float* __restrict__ out){
  int i = blockIdx.x;
  int h = threadIdx.x >> 6, lane = threadIdx.x & 63;
  int r0 = rowstart[i], r1 = rowstart[i + 1];
  int deg = r1 - r0;
  int total = deg + 1;                         // + self loop
  float adsti = a_dst[i * HEADS + h];
  const unsigned short* xbase = XPh + h * OUTC + lane;
  float acc = 0.f;

  if (total <= 64){
    // lane e owns edge e (e==deg -> self loop)
    int j = i;
    if (lane < deg) j = csr[r0 + lane];
    float a = -1e30f;
    if (lane < total){
      a = a_src[j * HEADS + h] + adsti;
      a = (a > 0.f) ? a : NEG * a;
    }
    float m = a;
    #pragma unroll
    for (int msk = 32; msk; msk >>= 1) m = fmaxf(m, __shfl_xor(m, msk, 64));
    float p = (lane < total) ? __expf(a - m) : 0.f;
    float s = p;
    #pragma unroll
    for (int msk = 32; msk; msk >>= 1) s += __shfl_xor(s, msk, 64);
    float coef = p * (1.f / s);
    int ji = j;
    unsigned int cu = __float_as_uint(coef);
    for (int e = 0; e < total; ++e){
      int jj = __builtin_amdgcn_readlane(ji, e);
      float cc = __uint_as_float((unsigned int)__builtin_amdgcn_readlane((int)cu, e));
      acc += cc * bf2f(xbase[(size_t)jj * HC]);
    }
  } else {
    // generic online-softmax path (rare)
    float m = -1e30f, s = 0.f;
    for (int e = lane; e < total; e += 64){
      int j = (e < deg) ? csr[r0 + e] : i;
      float a = a_src[j * HEADS + h] + adsti;
      a = (a > 0.f) ? a : NEG * a;
      if (a > m){ s = s * __expf(m - a) + 1.f; m = a; }
      else        s += __expf(a - m);
    }
    #pragma unroll
    for (int msk = 32; msk; msk >>= 1){
      float m2 = __shfl_xor(m, msk, 64);
      float s2 = __shfl_xor(s, msk, 64);
      float M = fmaxf(m, m2);
      float ns = 0.f;
      if (m  > -1e29f) ns += s  * __expf(m  - M);
      if (m2 > -1e29f) ns += s2 * __expf(m2 - M);
      m = M; s = ns;
    }
    float inv_s = 1.f / s;
    for (int e = 0; e < total; ++e){
      int j = (e < deg) ? csr[r0 + e] : i;
      float a = a_src[j * HEADS + h] + adsti;
      a = (a > 0.f) ? a : NEG * a;
      float coef = __expf(a - m) * inv_s;
      acc += coef * bf2f(xbase[(size_t)j * HC]);
    }
  }
  out[(size_t)i * HC + h * OUTC + lane] = acc + bias[h * OUTC + lane];
}

extern "C" void kernel_launch(void* const* d_in, const int* in_sizes, int n_in,
                              void* d_out, int out_size, void* d_ws, size_t ws_size,
                              hipStream_t stream){
  const float* x       = (const float*)d_in[0];
  const float* W       = (const float*)d_in[1];
  const float* att_src = (const float*)d_in[2];
  const float* att_dst = (const float*)d_in[3];
  const float* bias    = (const float*)d_in[4];
  const int*   ei      = (const int*)d_in[5];
  int N = in_sizes[0] / INC;     // 50000
  int E = in_sizes[5] / 2;       // 800000

  char* p = (char*)d_ws;
  auto alloc = [&](size_t bytes)->char*{
    char* r = p; p += (bytes + 255) & ~(size_t)255; return r;
  };
  unsigned short* Xhi  = (unsigned short*)alloc((size_t)N * INC * 2);
  unsigned short* Xlo  = (unsigned short*)alloc((size_t)N * INC * 2);
  unsigned short* Wthi = (unsigned short*)alloc((size_t)INC * HC * 2);
  unsigned short* Wtlo = (unsigned short*)alloc((size_t)INC * HC * 2);
  unsigned short* XPh  = (unsigned short*)alloc((size_t)N * HC * 2);
  float* aSrc          = (float*)alloc((size_t)N * HEADS * 4);
  float* aDst          = (float*)alloc((size_t)N * HEADS * 4);
  int* deg             = (int*)alloc((size_t)N * 4);
  int* cursor          = (int*)alloc((size_t)N * 4);
  int* rowstart        = (int*)alloc(((size_t)N + 1) * 4);
  int* srcc            = (int*)alloc((size_t)E * 4);
  int* dstc            = (int*)alloc((size_t)E * 4);
  int* csr             = (int*)alloc((size_t)E * 4);
  int* bsum            = (int*)alloc(256 * 4);
  int* flags           = (int*)alloc(16);

  k_detect<<<1, 256, 0, stream>>>(ei, flags);
  k_conv_e<<<(E + 255) / 256, 256, 0, stream>>>(ei, flags, srcc, dstc, E);

  k_split_x<<<(N * INC + 255) / 256, 256, 0, stream>>>(x, Xhi, Xlo, N * INC);
  k_split_w<<<(INC * HC) / 256, 256, 0, stream>>>(W, Wthi, Wtlo);
  dim3 g(N / 16, HC / 64);
  k_gemm<<<g, 256, 0, stream>>>(Xhi, Xlo, Wthi, Wtlo, XPh);
  k_att<<<(N + 3) / 4, 256, 0, stream>>>(XPh, att_src, att_dst, aSrc, aDst, N);

  hipMemsetAsync(deg, 0, (size_t)N * 4, stream);
  hipMemsetAsync(cursor, 0, (size_t)N * 4, stream);
  k_hist<<<(E + 255) / 256, 256, 0, stream>>>(dstc, deg, E);
  int nb = (N + 1023) / 1024;
  k_scan1<<<nb, 256, 0, stream>>>(deg, rowstart, bsum, N);
  k_scan2<<<1, 64, 0, stream>>>(bsum, nb, rowstart, N);
  k_scan3<<<nb, 256, 0, stream>>>(rowstart, bsum, N);
  k_scatter<<<(E + 255) / 256, 256, 0, stream>>>(srcc, dstc, rowstart, cursor, csr, E);

  k_main<<<N, 256, 0, stream>>>(XPh, aSrc, aDst, rowstart, csr, bias,
                                (float*)d_out);
}

// Round 5
// 391.927 us; speedup vs baseline: 1.2780x; 1.2240x over previous
//
#include <hip/hip_runtime.h>

#define HEADS 4
#define OUTC 64
#define INC 128
#define HC 256   // HEADS*OUTC
#define NEG 0.2f

typedef __attribute__((ext_vector_type(8))) short bf16x8;
typedef __attribute__((ext_vector_type(4))) float f32x4;

static __device__ __forceinline__ float bf2f(unsigned short u){
  unsigned int x = ((unsigned int)u) << 16;
  return __uint_as_float(x);
}
static __device__ __forceinline__ unsigned short f2bf(float f){
  unsigned int x = __float_as_uint(f);
  unsigned int lsb = (x >> 16) & 1u;
  x += 0x7fffu + lsb;           // RNE
  return (unsigned short)(x >> 16);
}

// ---- edge-layout detection: flags[0]=1 if edge_index is int64-storage ----
__global__ void k_detect(const int* __restrict__ ei, int* __restrict__ flags){
  __shared__ int cnt;
  if (threadIdx.x == 0) cnt = 0;
  __syncthreads();
  int c = 0;
  for (int i = threadIdx.x; i < 2048; i += 256){
    if (ei[2 * i + 1] == 0) c++;
  }
  atomicAdd(&cnt, c);
  __syncthreads();
  if (threadIdx.x == 0) flags[0] = (cnt > 1900) ? 1 : 0;
}

// ---- edge canonicalize + degree histogram (merged) ----
__global__ void k_conv_e_hist(const int* __restrict__ ei, const int* __restrict__ flags,
                              int* __restrict__ srcc, int* __restrict__ dstc,
                              int* __restrict__ deg, int E){
  int e = blockIdx.x * 256 + threadIdx.x;
  if (e < E){
    int s, d;
    if (flags[0]){ s = ei[2 * e]; d = ei[2 * E + 2 * e]; }
    else         { s = ei[e];     d = ei[E + e]; }
    srcc[e] = s; dstc[e] = d;
    atomicAdd(&deg[d], 1);
  }
}

// ---- split x and W (transposed) into bf16 hi/lo, one kernel ----
// blocks [0,128): W (32768 elems); blocks [128, 128+N*INC/256): x
__global__ void k_split(const float* __restrict__ X, const float* __restrict__ W,
                        unsigned short* __restrict__ Xhi, unsigned short* __restrict__ Xlo,
                        unsigned short* __restrict__ Wthi, unsigned short* __restrict__ Wtlo){
  int bid = blockIdx.x;
  if (bid < 128){
    int t = bid * 256 + threadIdx.x;           // 0..32767
    int k = t >> 8, n = t & 255;
    float v = W[t];
    unsigned short hi = f2bf(v);
    Wthi[n * INC + k] = hi;
    Wtlo[n * INC + k] = f2bf(v - bf2f(hi));
  } else {
    int i = (bid - 128) * 256 + threadIdx.x;
    float v = X[i];
    unsigned short hi = f2bf(v);
    Xhi[i] = hi;
    Xlo[i] = f2bf(v - bf2f(hi));
  }
}

// ---- MFMA GEMM (split bf16 ~= fp32): XPh[N,256] (bf16) = X @ W ----
__global__ __launch_bounds__(256) void k_gemm(const unsigned short* __restrict__ Xhi,
    const unsigned short* __restrict__ Xlo, const unsigned short* __restrict__ Wthi,
    const unsigned short* __restrict__ Wtlo, unsigned short* __restrict__ XPh){
  int w = threadIdx.x >> 6, lane = threadIdx.x & 63;
  int m0 = blockIdx.x * 16;
  int colg = blockIdx.y * 64 + w * 16 + (lane & 15);
  int quad = lane >> 4;
  int row  = m0 + (lane & 15);
  size_t aoff = (size_t)row  * INC + quad * 8;
  size_t boff = (size_t)colg * INC + quad * 8;
  f32x4 acc = {0.f, 0.f, 0.f, 0.f};
  #pragma unroll
  for (int kk = 0; kk < 4; ++kk){
    bf16x8 ah = *(const bf16x8*)(Xhi  + aoff + kk * 32);
    bf16x8 al = *(const bf16x8*)(Xlo  + aoff + kk * 32);
    bf16x8 bh = *(const bf16x8*)(Wthi + boff + kk * 32);
    bf16x8 bl = *(const bf16x8*)(Wtlo + boff + kk * 32);
    acc = __builtin_amdgcn_mfma_f32_16x16x32_bf16(ah, bh, acc, 0, 0, 0);
    acc = __builtin_amdgcn_mfma_f32_16x16x32_bf16(ah, bl, acc, 0, 0, 0);
    acc = __builtin_amdgcn_mfma_f32_16x16x32_bf16(al, bh, acc, 0, 0, 0);
  }
  #pragma unroll
  for (int r = 0; r < 4; ++r){
    XPh[(size_t)(m0 + quad * 4 + r) * HC + colg] = f2bf(acc[r]);
  }
}

// ---- logits: wave = one node ----
__global__ __launch_bounds__(256) void k_att(const unsigned short* __restrict__ XPh,
    const float* __restrict__ att_src, const float* __restrict__ att_dst,
    float* __restrict__ a_src, float* __restrict__ a_dst, int N){
  int w = threadIdx.x >> 6, lane = threadIdx.x & 63;
  int n = blockIdx.x * 4 + w;
  if (n >= N) return;
  int h = lane >> 4, cg = (lane & 15) * 4;
  ushort4 uv = *(const ushort4*)&XPh[(size_t)n * HC + lane * 4];
  float4 as4 = *(const float4*)&att_src[h * OUTC + cg];
  float4 ad4 = *(const float4*)&att_dst[h * OUTC + cg];
  float x0 = bf2f(uv.x), x1 = bf2f(uv.y), x2 = bf2f(uv.z), x3 = bf2f(uv.w);
  float ps = x0 * as4.x + x1 * as4.y + x2 * as4.z + x3 * as4.w;
  float pd = x0 * ad4.x + x1 * ad4.y + x2 * ad4.z + x3 * ad4.w;
  #pragma unroll
  for (int m = 1; m < 16; m <<= 1){
    ps += __shfl_xor(ps, m, 64);
    pd += __shfl_xor(pd, m, 64);
  }
  if ((lane & 15) == 0){
    a_src[n * HEADS + h] = ps;
    a_dst[n * HEADS + h] = pd;
  }
}

// ---- exclusive scan over deg (rowstart WITHOUT self-loops; +i added at use) ----
__global__ __launch_bounds__(256) void k_scan1(const int* __restrict__ deg,
                                               int* __restrict__ out,
                                               int* __restrict__ bsum, int N){
  __shared__ int tsum[256];
  int t = threadIdx.x;
  int base = blockIdx.x * 1024 + t * 4;
  int v[4]; int s = 0;
  #pragma unroll
  for (int k = 0; k < 4; ++k){ int i = base + k; v[k] = (i < N) ? deg[i] : 0; s += v[k]; }
  tsum[t] = s;
  __syncthreads();
  for (int off = 1; off < 256; off <<= 1){
    int x = (t >= off) ? tsum[t - off] : 0;
    __syncthreads();
    tsum[t] += x;
    __syncthreads();
  }
  int excl = tsum[t] - s;
  if (t == 255) bsum[blockIdx.x] = tsum[255];
  int run = excl;
  #pragma unroll
  for (int k = 0; k < 4; ++k){ int i = base + k; if (i < N) out[i] = run; run += v[k]; }
}
__global__ void k_scan2(int* __restrict__ bsum, int nb, int* __restrict__ rowstart, int N){
  if (threadIdx.x == 0){
    int run = 0;
    for (int i = 0; i < nb; ++i){ int v = bsum[i]; bsum[i] = run; run += v; }
    rowstart[N] = run;
  }
}
__global__ __launch_bounds__(256) void k_scan3(int* __restrict__ rowstart,
                                               const int* __restrict__ bsum, int N){
  int off = bsum[blockIdx.x];
  int base = blockIdx.x * 1024 + threadIdx.x * 4;
  #pragma unroll
  for (int k = 0; k < 4; ++k){ int i = base + k; if (i < N) rowstart[i] += off; }
}

// ---- scatter edges; CSR slot base = rowstart[d] + d (self slot appended last) ----
__global__ void k_scatter(const int* __restrict__ src, const int* __restrict__ dst,
                          const int* __restrict__ rowstart, int* __restrict__ cursor,
                          int* __restrict__ csr, int E){
  int e = blockIdx.x * 256 + threadIdx.x;
  if (e < E){
    int d = dst[e];
    int pos = rowstart[d] + d + atomicAdd(&cursor[d], 1);
    csr[pos] = src[e];
  }
}

// ---- coefs: block = node, wave = head, lane = CSR slot. Writes coefA[slot*4+h],
// and head-0 wave writes the self-loop CSR entry. ----
__global__ __launch_bounds__(256) void k_coef(const float* __restrict__ a_src,
    const float* __restrict__ a_dst, const int* __restrict__ rowstart,
    int* __restrict__ csr, float* __restrict__ coefA){
  int i = blockIdx.x;
  int h = threadIdx.x >> 6, lane = threadIdx.x & 63;
  int rs = rowstart[i], re = rowstart[i + 1];
  int deg = re - rs;
  int r0 = rs + i;
  int total = deg + 1;
  float adsti = a_dst[i * HEADS + h];

  if (total <= 64){
    int j = i;
    if (lane < deg) j = csr[r0 + lane];
    if (h == 0 && lane == deg) csr[r0 + deg] = i;
    float a = -1e30f;
    if (lane < total){
      a = a_src[j * HEADS + h] + adsti;
      a = (a > 0.f) ? a : NEG * a;
    }
    float m = a;
    #pragma unroll
    for (int msk = 32; msk; msk >>= 1) m = fmaxf(m, __shfl_xor(m, msk, 64));
    float p = (lane < total) ? __expf(a - m) : 0.f;
    float s = p;
    #pragma unroll
    for (int msk = 32; msk; msk >>= 1) s += __shfl_xor(s, msk, 64);
    if (lane < total) coefA[(size_t)(r0 + lane) * 4 + h] = p / s;
  } else {
    float m = -1e30f, s = 0.f;
    for (int e = lane; e < total; e += 64){
      int j = i;
      if (e < deg) j = csr[r0 + e];
      else if (h == 0) csr[r0 + deg] = i;
      float a = a_src[j * HEADS + h] + adsti;
      a = (a > 0.f) ? a : NEG * a;
      if (a > m){ s = s * __expf(m - a) + 1.f; m = a; }
      else        s += __expf(a - m);
    }
    #pragma unroll
    for (int msk = 32; msk; msk >>= 1){
      float m2 = __shfl_xor(m, msk, 64);
      float s2 = __shfl_xor(s, msk, 64);
      float M = fmaxf(m, m2);
      float ns = 0.f;
      if (m  > -1e29f) ns += s  * __expf(m  - M);
      if (m2 > -1e29f) ns += s2 * __expf(m2 - M);
      m = M; s = ns;
    }
    float inv_s = 1.f / s;
    for (int e = lane; e < total; e += 64){
      int j = (e < deg) ? csr[r0 + e] : i;
      float a = a_src[j * HEADS + h] + adsti;
      a = (a > 0.f) ? a : NEG * a;
      coefA[(size_t)(r0 + e) * 4 + h] = __expf(a - m) * inv_s;
    }
  }
}

// ---- gather: wave = node, lane owns channels [lane*4, lane*4+4) (head lane>>4).
// One 512B row load per edge; 4-way unrolled for MLP. ----
__global__ __launch_bounds__(256) void k_gather(const unsigned short* __restrict__ XPh,
    const int* __restrict__ rowstart, const int* __restrict__ csr,
    const float* __restrict__ coefA, const float* __restrict__ bias,
    float* __restrict__ out, int N){
  int w = threadIdx.x >> 6, lane = threadIdx.x & 63;
  int n = blockIdx.x * 4 + w;
  if (n >= N) return;
  int r0 = rowstart[n] + n;
  int r1 = rowstart[n + 1] + n + 1;
  int h = lane >> 4;
  const unsigned short* xb = XPh + lane * 4;
  float a0 = 0.f, a1 = 0.f, a2 = 0.f, a3 = 0.f;
  int e = r0;
  for (; e + 4 <= r1; e += 4){
    int j0 = csr[e], j1 = csr[e + 1], j2 = csr[e + 2], j3 = csr[e + 3];
    float c0 = coefA[(size_t)e * 4 + h];
    float c1 = coefA[(size_t)(e + 1) * 4 + h];
    float c2 = coefA[(size_t)(e + 2) * 4 + h];
    float c3 = coefA[(size_t)(e + 3) * 4 + h];
    ushort4 x0 = *(const ushort4*)(xb + (size_t)j0 * HC);
    ushort4 x1 = *(const ushort4*)(xb + (size_t)j1 * HC);
    ushort4 x2 = *(const ushort4*)(xb + (size_t)j2 * HC);
    ushort4 x3 = *(const ushort4*)(xb + (size_t)j3 * HC);
    a0 += c0 * bf2f(x0.x); a1 += c0 * bf2f(x0.y); a2 += c0 * bf2f(x0.z); a3 += c0 * bf2f(x0.w);
    a0 += c1 * bf2f(x1.x); a1 += c1 * bf2f(x1.y); a2 += c1 * bf2f(x1.z); a3 += c1 * bf2f(x1.w);
    a0 += c2 * bf2f(x2.x); a1 += c2 * bf2f(x2.y); a2 += c2 * bf2f(x2.z); a3 += c2 * bf2f(x2.w);
    a0 += c3 * bf2f(x3.x); a1 += c3 * bf2f(x3.y); a2 += c3 * bf2f(x3.z); a3 += c3 * bf2f(x3.w);
  }
  for (; e < r1; ++e){
    int j = csr[e];
    float c = coefA[(size_t)e * 4 + h];
    ushort4 xv = *(const ushort4*)(xb + (size_t)j * HC);
    a0 += c * bf2f(xv.x); a1 += c * bf2f(xv.y); a2 += c * bf2f(xv.z); a3 += c * bf2f(xv.w);
  }
  float4 b4 = *(const float4*)&bias[lane * 4];
  float4 r; r.x = a0 + b4.x; r.y = a1 + b4.y; r.z = a2 + b4.z; r.w = a3 + b4.w;
  *(float4*)&out[(size_t)n * HC + lane * 4] = r;
}

extern "C" void kernel_launch(void* const* d_in, const int* in_sizes, int n_in,
                              void* d_out, int out_size, void* d_ws, size_t ws_size,
                              hipStream_t stream){
  const float* x       = (const float*)d_in[0];
  const float* W       = (const float*)d_in[1];
  const float* att_src = (const float*)d_in[2];
  const float* att_dst = (const float*)d_in[3];
  const float* bias    = (const float*)d_in[4];
  const int*   ei      = (const int*)d_in[5];
  int N = in_sizes[0] / INC;     // 50000
  int E = in_sizes[5] / 2;       // 800000

  char* p = (char*)d_ws;
  auto alloc = [&](size_t bytes)->char*{
    char* r = p; p += (bytes + 255) & ~(size_t)255; return r;
  };
  unsigned short* Xhi  = (unsigned short*)alloc((size_t)N * INC * 2);
  unsigned short* Xlo  = (unsigned short*)alloc((size_t)N * INC * 2);
  unsigned short* Wthi = (unsigned short*)alloc((size_t)INC * HC * 2);
  unsigned short* Wtlo = (unsigned short*)alloc((size_t)INC * HC * 2);
  unsigned short* XPh  = (unsigned short*)alloc((size_t)N * HC * 2);
  float* aSrc          = (float*)alloc((size_t)N * HEADS * 4);
  float* aDst          = (float*)alloc((size_t)N * HEADS * 4);
  int* degcur          = (int*)alloc((size_t)2 * N * 4);   // deg | cursor, one memset
  int* deg             = degcur;
  int* cursor          = degcur + N;
  int* rowstart        = (int*)alloc(((size_t)N + 1) * 4);
  int* srcc            = (int*)alloc((size_t)E * 4);
  int* dstc            = (int*)alloc((size_t)E * 4);
  int* csr             = (int*)alloc(((size_t)E + N) * 4);
  float* coefA         = (float*)alloc(((size_t)E + N) * 4 * 4);
  int* bsum            = (int*)alloc(256 * 4);
  int* flags           = (int*)alloc(16);

  hipMemsetAsync(degcur, 0, (size_t)2 * N * 4, stream);
  k_detect<<<1, 256, 0, stream>>>(ei, flags);
  k_conv_e_hist<<<(E + 255) / 256, 256, 0, stream>>>(ei, flags, srcc, dstc, deg, E);

  k_split<<<128 + (N * INC) / 256, 256, 0, stream>>>(x, W, Xhi, Xlo, Wthi, Wtlo);
  dim3 g(N / 16, HC / 64);
  k_gemm<<<g, 256, 0, stream>>>(Xhi, Xlo, Wthi, Wtlo, XPh);
  k_att<<<(N + 3) / 4, 256, 0, stream>>>(XPh, att_src, att_dst, aSrc, aDst, N);

  int nb = (N + 1023) / 1024;
  k_scan1<<<nb, 256, 0, stream>>>(deg, rowstart, bsum, N);
  k_scan2<<<1, 64, 0, stream>>>(bsum, nb, rowstart, N);
  k_scan3<<<nb, 256, 0, stream>>>(rowstart, bsum, N);
  k_scatter<<<(E + 255) / 256, 256, 0, stream>>>(srcc, dstc, rowstart, cursor, csr, E);

  k_coef<<<N, 256, 0, stream>>>(aSrc, aDst, rowstart, csr, coefA);
  k_gather<<<(N + 3) / 4, 256, 0, stream>>>(XPh, rowstart, csr, coefA, bias,
                                            (float*)d_out, N);
}

// Round 6
// 319.498 us; speedup vs baseline: 1.5678x; 1.2267x over previous
//
#include <hip/hip_runtime.h>

#define HEADS 4
#define OUTC 64
#define INC 128
#define HC 256   // HEADS*OUTC
#define NEG 0.2f

typedef __attribute__((ext_vector_type(8))) short bf16x8;
typedef __attribute__((ext_vector_type(4))) float f32x4;

static __device__ __forceinline__ float bf2f(unsigned short u){
  unsigned int x = ((unsigned int)u) << 16;
  return __uint_as_float(x);
}
static __device__ __forceinline__ unsigned short f2bf(float f){
  unsigned int x = __float_as_uint(f);
  unsigned int lsb = (x >> 16) & 1u;
  x += 0x7fffu + lsb;           // RNE
  return (unsigned short)(x >> 16);
}
static __device__ __forceinline__ void split8(float4 a, float4 b, bf16x8& hi, bf16x8& lo){
  float v[8] = {a.x, a.y, a.z, a.w, b.x, b.y, b.z, b.w};
  #pragma unroll
  for (int i = 0; i < 8; ++i){
    unsigned short h = f2bf(v[i]);
    hi[i] = (short)h;
    lo[i] = (short)f2bf(v[i] - bf2f(h));
  }
}

// ---- edge-layout detection: flags[0]=1 if edge_index is int64-storage ----
__global__ void k_detect(const int* __restrict__ ei, int* __restrict__ flags){
  __shared__ int cnt;
  if (threadIdx.x == 0) cnt = 0;
  __syncthreads();
  int c = 0;
  for (int i = threadIdx.x; i < 2048; i += 256){
    if (ei[2 * i + 1] == 0) c++;
  }
  atomicAdd(&cnt, c);
  __syncthreads();
  if (threadIdx.x == 0) flags[0] = (cnt > 1900) ? 1 : 0;
}

// ---- edge canonicalize + degree histogram ----
__global__ void k_conv_e_hist(const int* __restrict__ ei, const int* __restrict__ flags,
                              int* __restrict__ srcc, int* __restrict__ dstc,
                              int* __restrict__ deg, int E){
  int e = blockIdx.x * 256 + threadIdx.x;
  if (e < E){
    int s, d;
    if (flags[0]){ s = ei[2 * e]; d = ei[2 * E + 2 * e]; }
    else         { s = ei[e];     d = ei[E + e]; }
    srcc[e] = s; dstc[e] = d;
    atomicAdd(&deg[d], 1);
  }
}

// ---- split + transpose W only (x handled in-gemm) ----
__global__ void k_split_w(const float* __restrict__ W, unsigned short* __restrict__ Wthi,
                          unsigned short* __restrict__ Wtlo){
  int t = blockIdx.x * 256 + threadIdx.x;      // 0..32767
  int k = t >> 8, n = t & 255;
  float v = W[t];
  unsigned short hi = f2bf(v);
  Wthi[n * INC + k] = hi;
  Wtlo[n * INC + k] = f2bf(v - bf2f(hi));
}

// ---- fused GEMM + attention logits ----
// grid N/16; block 256 = 4 waves. Wave w = head w (cols [w*64,(w+1)*64), 4 tiles).
// A loaded fp32 from x and split hi/lo in-register. Epilogue: a_src/a_dst from acc.
__global__ __launch_bounds__(256, 2) void k_gemm_fused(const float* __restrict__ X,
    const unsigned short* __restrict__ Wthi, const unsigned short* __restrict__ Wtlo,
    const float* __restrict__ att_src, const float* __restrict__ att_dst,
    unsigned short* __restrict__ XPh, float* __restrict__ a_src, float* __restrict__ a_dst){
  int w = threadIdx.x >> 6, lane = threadIdx.x & 63;
  int m0 = blockIdx.x * 16;
  int quad = lane >> 4;
  int row_a = m0 + (lane & 15);
  int colg[4];
  #pragma unroll
  for (int t = 0; t < 4; ++t) colg[t] = w * 64 + t * 16 + (lane & 15);

  f32x4 acc[4];
  #pragma unroll
  for (int t = 0; t < 4; ++t) acc[t] = (f32x4){0.f, 0.f, 0.f, 0.f};

  const float* xrow = X + (size_t)row_a * INC + quad * 8;
  #pragma unroll
  for (int kk = 0; kk < 4; ++kk){
    float4 va = *(const float4*)(xrow + kk * 32);
    float4 vb = *(const float4*)(xrow + kk * 32 + 4);
    bf16x8 ah, al;
    split8(va, vb, ah, al);
    #pragma unroll
    for (int t = 0; t < 4; ++t){
      const bf16x8 bh = *(const bf16x8*)(Wthi + (size_t)colg[t] * INC + kk * 32 + quad * 8);
      const bf16x8 bl = *(const bf16x8*)(Wtlo + (size_t)colg[t] * INC + kk * 32 + quad * 8);
      acc[t] = __builtin_amdgcn_mfma_f32_16x16x32_bf16(ah, bh, acc[t], 0, 0, 0);
      acc[t] = __builtin_amdgcn_mfma_f32_16x16x32_bf16(ah, bl, acc[t], 0, 0, 0);
      acc[t] = __builtin_amdgcn_mfma_f32_16x16x32_bf16(al, bh, acc[t], 0, 0, 0);
    }
  }

  // store XPh (bf16). C/D layout: col=lane&15, row=quad*4+r
  #pragma unroll
  for (int t = 0; t < 4; ++t){
    #pragma unroll
    for (int r = 0; r < 4; ++r){
      XPh[(size_t)(m0 + quad * 4 + r) * HC + colg[t]] = f2bf(acc[t][r]);
    }
  }

  // epilogue: head-w logits. as/ad per tile (4B loads, cached)
  float as[4], ad[4];
  #pragma unroll
  for (int t = 0; t < 4; ++t){
    as[t] = att_src[colg[t]];
    ad[t] = att_dst[colg[t]];
  }
  float ps[4], pd[4];
  #pragma unroll
  for (int r = 0; r < 4; ++r){
    ps[r] = acc[0][r] * as[0] + acc[1][r] * as[1] + acc[2][r] * as[2] + acc[3][r] * as[3];
    pd[r] = acc[0][r] * ad[0] + acc[1][r] * ad[1] + acc[2][r] * ad[2] + acc[3][r] * ad[3];
  }
  #pragma unroll
  for (int msk = 1; msk < 16; msk <<= 1){
    #pragma unroll
    for (int r = 0; r < 4; ++r){
      ps[r] += __shfl_xor(ps[r], msk, 64);
      pd[r] += __shfl_xor(pd[r], msk, 64);
    }
  }
  if ((lane & 15) == 0){
    #pragma unroll
    for (int r = 0; r < 4; ++r){
      int n = m0 + quad * 4 + r;
      a_src[n * HEADS + w] = ps[r];
      a_dst[n * HEADS + w] = pd[r];
    }
  }
}

// ---- exclusive scan over deg ----
__global__ __launch_bounds__(256) void k_scan1(const int* __restrict__ deg,
                                               int* __restrict__ out,
                                               int* __restrict__ bsum, int N){
  __shared__ int tsum[256];
  int t = threadIdx.x;
  int base = blockIdx.x * 1024 + t * 4;
  int v[4]; int s = 0;
  #pragma unroll
  for (int k = 0; k < 4; ++k){ int i = base + k; v[k] = (i < N) ? deg[i] : 0; s += v[k]; }
  tsum[t] = s;
  __syncthreads();
  for (int off = 1; off < 256; off <<= 1){
    int x = (t >= off) ? tsum[t - off] : 0;
    __syncthreads();
    tsum[t] += x;
    __syncthreads();
  }
  int excl = tsum[t] - s;
  if (t == 255) bsum[blockIdx.x] = tsum[255];
  int run = excl;
  #pragma unroll
  for (int k = 0; k < 4; ++k){ int i = base + k; if (i < N) out[i] = run; run += v[k]; }
}
__global__ void k_scan2(int* __restrict__ bsum, int nb, int* __restrict__ rowstart, int N){
  if (threadIdx.x == 0){
    int run = 0;
    for (int i = 0; i < nb; ++i){ int v = bsum[i]; bsum[i] = run; run += v; }
    rowstart[N] = run;
  }
}
__global__ __launch_bounds__(256) void k_scan3(int* __restrict__ rowstart,
                                               const int* __restrict__ bsum, int N){
  int off = bsum[blockIdx.x];
  int base = blockIdx.x * 1024 + threadIdx.x * 4;
  #pragma unroll
  for (int k = 0; k < 4; ++k){ int i = base + k; if (i < N) rowstart[i] += off; }
}

__global__ void k_scatter(const int* __restrict__ src, const int* __restrict__ dst,
                          const int* __restrict__ rowstart, int* __restrict__ cursor,
                          int* __restrict__ csr, int E){
  int e = blockIdx.x * 256 + threadIdx.x;
  if (e < E){
    int d = dst[e];
    int pos = rowstart[d] + atomicAdd(&cursor[d], 1);
    csr[pos] = src[e];
  }
}

// ---- fused softmax-coef + gather: wave = node (all 4 heads) ----
__global__ __launch_bounds__(256) void k_fused(const unsigned short* __restrict__ XPh,
    const float* __restrict__ a_src, const float* __restrict__ a_dst,
    const int* __restrict__ rowstart, const int* __restrict__ csr,
    const float* __restrict__ bias, float* __restrict__ out, int N){
  __shared__ float sh[4][64][4];               // [wave][slot][head]
  int w = threadIdx.x >> 6, lane = threadIdx.x & 63;
  int n = blockIdx.x * 4 + w;
  bool alive = (n < N);
  if (!alive) n = 0;
  int r0 = rowstart[n], r1 = rowstart[n + 1];
  int deg = r1 - r0;
  int total = deg + 1;                         // + self loop (in-register)
  int h = lane >> 4;
  float4 ad4 = *(const float4*)&a_dst[n * HEADS];
  bool fast = (total <= 64);
  int jv = n;
  float msel = 0.f, inv_sel = 0.f;             // slow-path per-lane head state

  if (fast){
    if (lane < deg) jv = csr[r0 + lane];
    float l0 = -1e30f, l1 = -1e30f, l2 = -1e30f, l3 = -1e30f;
    if (lane < total){
      float4 a4 = *(const float4*)&a_src[jv * HEADS];
      l0 = a4.x + ad4.x; l0 = (l0 > 0.f) ? l0 : NEG * l0;
      l1 = a4.y + ad4.y; l1 = (l1 > 0.f) ? l1 : NEG * l1;
      l2 = a4.z + ad4.z; l2 = (l2 > 0.f) ? l2 : NEG * l2;
      l3 = a4.w + ad4.w; l3 = (l3 > 0.f) ? l3 : NEG * l3;
    }
    float m0 = l0, m1 = l1, m2 = l2, m3 = l3;
    #pragma unroll
    for (int msk = 32; msk; msk >>= 1){
      m0 = fmaxf(m0, __shfl_xor(m0, msk, 64));
      m1 = fmaxf(m1, __shfl_xor(m1, msk, 64));
      m2 = fmaxf(m2, __shfl_xor(m2, msk, 64));
      m3 = fmaxf(m3, __shfl_xor(m3, msk, 64));
    }
    float p0 = 0.f, p1 = 0.f, p2 = 0.f, p3 = 0.f;
    if (lane < total){
      p0 = __expf(l0 - m0); p1 = __expf(l1 - m1);
      p2 = __expf(l2 - m2); p3 = __expf(l3 - m3);
    }
    float s0 = p0, s1 = p1, s2 = p2, s3 = p3;
    #pragma unroll
    for (int msk = 32; msk; msk >>= 1){
      s0 += __shfl_xor(s0, msk, 64);
      s1 += __shfl_xor(s1, msk, 64);
      s2 += __shfl_xor(s2, msk, 64);
      s3 += __shfl_xor(s3, msk, 64);
    }
    if (lane < total){
      sh[w][lane][0] = p0 / s0;
      sh[w][lane][1] = p1 / s1;
      sh[w][lane][2] = p2 / s2;
      sh[w][lane][3] = p3 / s3;
    }
  } else {
    // slow path (deg>63): 4-head online softmax, lane-strided
    float m[4] = {-1e30f, -1e30f, -1e30f, -1e30f};
    float s[4] = {0.f, 0.f, 0.f, 0.f};
    float adArr[4] = {ad4.x, ad4.y, ad4.z, ad4.w};
    for (int e = lane; e < total; e += 64){
      int j = (e < deg) ? csr[r0 + e] : n;
      float4 a4 = *(const float4*)&a_src[j * HEADS];
      float aa[4] = {a4.x, a4.y, a4.z, a4.w};
      #pragma unroll
      for (int hh = 0; hh < 4; ++hh){
        float l = aa[hh] + adArr[hh];
        l = (l > 0.f) ? l : NEG * l;
        if (l > m[hh]){ s[hh] = s[hh] * __expf(m[hh] - l) + 1.f; m[hh] = l; }
        else            s[hh] += __expf(l - m[hh]);
      }
    }
    #pragma unroll
    for (int hh = 0; hh < 4; ++hh){
      float mm = m[hh], ss = s[hh];
      #pragma unroll
      for (int msk = 32; msk; msk >>= 1){
        float m2 = __shfl_xor(mm, msk, 64);
        float s2 = __shfl_xor(ss, msk, 64);
        float M = fmaxf(mm, m2);
        float ns = 0.f;
        if (mm > -1e29f) ns += ss * __expf(mm - M);
        if (m2 > -1e29f) ns += s2 * __expf(m2 - M);
        mm = M; ss = ns;
      }
      m[hh] = mm; s[hh] = ss;
    }
    msel   = (h == 0) ? m[0] : (h == 1) ? m[1] : (h == 2) ? m[2] : m[3];
    inv_sel = 1.f / ((h == 0) ? s[0] : (h == 1) ? s[1] : (h == 2) ? s[2] : s[3]);
  }

  __syncthreads();   // all waves reach exactly once (both paths)

  float a0 = 0.f, a1 = 0.f, a2 = 0.f, a3 = 0.f;
  const unsigned short* xb = XPh + lane * 4;
  if (fast){
    int e = 0;
    for (; e + 4 <= total; e += 4){
      int ja = __builtin_amdgcn_readlane(jv, e);
      int jb = __builtin_amdgcn_readlane(jv, e + 1);
      int jc = __builtin_amdgcn_readlane(jv, e + 2);
      int jd = __builtin_amdgcn_readlane(jv, e + 3);
      float ca = sh[w][e][h], cb = sh[w][e + 1][h];
      float cc = sh[w][e + 2][h], cd = sh[w][e + 3][h];
      ushort4 xa = *(const ushort4*)(xb + (size_t)ja * HC);
      ushort4 x1 = *(const ushort4*)(xb + (size_t)jb * HC);
      ushort4 x2 = *(const ushort4*)(xb + (size_t)jc * HC);
      ushort4 x3 = *(const ushort4*)(xb + (size_t)jd * HC);
      a0 += ca * bf2f(xa.x); a1 += ca * bf2f(xa.y); a2 += ca * bf2f(xa.z); a3 += ca * bf2f(xa.w);
      a0 += cb * bf2f(x1.x); a1 += cb * bf2f(x1.y); a2 += cb * bf2f(x1.z); a3 += cb * bf2f(x1.w);
      a0 += cc * bf2f(x2.x); a1 += cc * bf2f(x2.y); a2 += cc * bf2f(x2.z); a3 += cc * bf2f(x2.w);
      a0 += cd * bf2f(x3.x); a1 += cd * bf2f(x3.y); a2 += cd * bf2f(x3.z); a3 += cd * bf2f(x3.w);
    }
    for (; e < total; ++e){
      int j = __builtin_amdgcn_readlane(jv, e);
      float c = sh[w][e][h];
      ushort4 xv = *(const ushort4*)(xb + (size_t)j * HC);
      a0 += c * bf2f(xv.x); a1 += c * bf2f(xv.y); a2 += c * bf2f(xv.z); a3 += c * bf2f(xv.w);
    }
  } else {
    float adh = (h == 0) ? ad4.x : (h == 1) ? ad4.y : (h == 2) ? ad4.z : ad4.w;
    for (int e = 0; e < total; ++e){
      int j = (e < deg) ? csr[r0 + e] : n;
      float4 a4 = *(const float4*)&a_src[j * HEADS];
      float ah = (h == 0) ? a4.x : (h == 1) ? a4.y : (h == 2) ? a4.z : a4.w;
      float l = ah + adh;
      l = (l > 0.f) ? l : NEG * l;
      float c = __expf(l - msel) * inv_sel;
      ushort4 xv = *(const ushort4*)(xb + (size_t)j * HC);
      a0 += c * bf2f(xv.x); a1 += c * bf2f(xv.y); a2 += c * bf2f(xv.z); a3 += c * bf2f(xv.w);
    }
  }
  if (alive){
    float4 b4 = *(const float4*)&bias[lane * 4];
    float4 r; r.x = a0 + b4.x; r.y = a1 + b4.y; r.z = a2 + b4.z; r.w = a3 + b4.w;
    *(float4*)&out[(size_t)n * HC + lane * 4] = r;
  }
}

extern "C" void kernel_launch(void* const* d_in, const int* in_sizes, int n_in,
                              void* d_out, int out_size, void* d_ws, size_t ws_size,
                              hipStream_t stream){
  const float* x       = (const float*)d_in[0];
  const float* W       = (const float*)d_in[1];
  const float* att_src = (const float*)d_in[2];
  const float* att_dst = (const float*)d_in[3];
  const float* bias    = (const float*)d_in[4];
  const int*   ei      = (const int*)d_in[5];
  int N = in_sizes[0] / INC;     // 50000
  int E = in_sizes[5] / 2;       // 800000

  char* p = (char*)d_ws;
  auto alloc = [&](size_t bytes)->char*{
    char* r = p; p += (bytes + 255) & ~(size_t)255; return r;
  };
  unsigned short* Wthi = (unsigned short*)alloc((size_t)INC * HC * 2);
  unsigned short* Wtlo = (unsigned short*)alloc((size_t)INC * HC * 2);
  unsigned short* XPh  = (unsigned short*)alloc((size_t)N * HC * 2);
  float* aSrc          = (float*)alloc((size_t)N * HEADS * 4);
  float* aDst          = (float*)alloc((size_t)N * HEADS * 4);
  int* degcur          = (int*)alloc((size_t)2 * N * 4);   // deg | cursor
  int* deg             = degcur;
  int* cursor          = degcur + N;
  int* rowstart        = (int*)alloc(((size_t)N + 1) * 4);
  int* srcc            = (int*)alloc((size_t)E * 4);
  int* dstc            = (int*)alloc((size_t)E * 4);
  int* csr             = (int*)alloc((size_t)E * 4);
  int* bsum            = (int*)alloc(256 * 4);
  int* flags           = (int*)alloc(16);

  hipMemsetAsync(degcur, 0, (size_t)2 * N * 4, stream);
  k_detect<<<1, 256, 0, stream>>>(ei, flags);
  k_conv_e_hist<<<(E + 255) / 256, 256, 0, stream>>>(ei, flags, srcc, dstc, deg, E);

  k_split_w<<<(INC * HC) / 256, 256, 0, stream>>>(W, Wthi, Wtlo);
  k_gemm_fused<<<N / 16, 256, 0, stream>>>(x, Wthi, Wtlo, att_src, att_dst,
                                           XPh, aSrc, aDst);

  int nb = (N + 1023) / 1024;
  k_scan1<<<nb, 256, 0, stream>>>(deg, rowstart, bsum, N);
  k_scan2<<<1, 64, 0, stream>>>(bsum, nb, rowstart, N);
  k_scan3<<<nb, 256, 0, stream>>>(rowstart, bsum, N);
  k_scatter<<<(E + 255) / 256, 256, 0, stream>>>(srcc, dstc, rowstart, cursor, csr, E);

  k_fused<<<(N + 3) / 4, 256, 0, stream>>>(XPh, aSrc, aDst, rowstart, csr, bias,
                                           (float*)d_out, N);
}

// Round 7
// 273.201 us; speedup vs baseline: 1.8334x; 1.1695x over previous
//
#include <hip/hip_runtime.h>

#define HEADS 4
#define OUTC 64
#define INC 128
#define HC 256   // HEADS*OUTC
#define NEG 0.2f

typedef __attribute__((ext_vector_type(8))) short bf16x8;
typedef __attribute__((ext_vector_type(4))) float f32x4;

static __device__ __forceinline__ float bf2f(unsigned short u){
  unsigned int x = ((unsigned int)u) << 16;
  return __uint_as_float(x);
}
static __device__ __forceinline__ unsigned short f2bf(float f){
  unsigned int x = __float_as_uint(f);
  unsigned int lsb = (x >> 16) & 1u;
  x += 0x7fffu + lsb;           // RNE
  return (unsigned short)(x >> 16);
}
static __device__ __forceinline__ void split8(float4 a, float4 b, bf16x8& hi, bf16x8& lo){
  float v[8] = {a.x, a.y, a.z, a.w, b.x, b.y, b.z, b.w};
  #pragma unroll
  for (int i = 0; i < 8; ++i){
    unsigned short h = f2bf(v[i]);
    hi[i] = (short)h;
    lo[i] = (short)f2bf(v[i] - bf2f(h));
  }
}

// ---- edge canonicalize (per-wave int64/int32 detection) + degree histogram.
// pos[e] = arrival order within dst bucket (from the atomic) -> scatter needs no atomics.
__global__ void k_conv_e_hist(const int* __restrict__ ei,
                              int* __restrict__ srcc, int* __restrict__ dstc,
                              int* __restrict__ pos, int* __restrict__ deg, int E){
  int e = blockIdx.x * 256 + threadIdx.x;
  bool valid = (e < E);
  int ee = valid ? e : 0;
  int hiw = ei[2 * ee + 1];                      // int64: high word (==0); int32: a node id
  bool hz = valid ? (hiw == 0) : true;
  unsigned long long mask = __ballot(hz);
  bool i64 = (mask == ~0ULL);                    // all 64 samples zero => int64 storage
  int s, d;
  if (i64){ s = ei[2 * ee]; d = ei[2 * (size_t)E + 2 * ee]; }
  else    { s = ei[ee];     d = ei[(size_t)E + ee]; }
  if (valid){
    srcc[e] = s; dstc[e] = d;
    pos[e] = atomicAdd(&deg[d], 1);
  }
}

// ---- split + transpose W into bf16 hi/lo ----
__global__ void k_split_w(const float* __restrict__ W, unsigned short* __restrict__ Wthi,
                          unsigned short* __restrict__ Wtlo){
  int t = blockIdx.x * 256 + threadIdx.x;        // 0..32767
  int k = t >> 8, n = t & 255;
  float v = W[t];
  unsigned short hi = f2bf(v);
  Wthi[n * INC + k] = hi;
  Wtlo[n * INC + k] = f2bf(v - bf2f(hi));
}

// ---- fused GEMM + attention logits ----
__global__ __launch_bounds__(256, 2) void k_gemm_fused(const float* __restrict__ X,
    const unsigned short* __restrict__ Wthi, const unsigned short* __restrict__ Wtlo,
    const float* __restrict__ att_src, const float* __restrict__ att_dst,
    unsigned short* __restrict__ XPh, float* __restrict__ a_src, float* __restrict__ a_dst){
  int w = threadIdx.x >> 6, lane = threadIdx.x & 63;
  int m0 = blockIdx.x * 16;
  int quad = lane >> 4;
  int row_a = m0 + (lane & 15);
  int colg[4];
  #pragma unroll
  for (int t = 0; t < 4; ++t) colg[t] = w * 64 + t * 16 + (lane & 15);

  f32x4 acc[4];
  #pragma unroll
  for (int t = 0; t < 4; ++t) acc[t] = (f32x4){0.f, 0.f, 0.f, 0.f};

  const float* xrow = X + (size_t)row_a * INC + quad * 8;
  #pragma unroll
  for (int kk = 0; kk < 4; ++kk){
    float4 va = *(const float4*)(xrow + kk * 32);
    float4 vb = *(const float4*)(xrow + kk * 32 + 4);
    bf16x8 ah, al;
    split8(va, vb, ah, al);
    #pragma unroll
    for (int t = 0; t < 4; ++t){
      const bf16x8 bh = *(const bf16x8*)(Wthi + (size_t)colg[t] * INC + kk * 32 + quad * 8);
      const bf16x8 bl = *(const bf16x8*)(Wtlo + (size_t)colg[t] * INC + kk * 32 + quad * 8);
      acc[t] = __builtin_amdgcn_mfma_f32_16x16x32_bf16(ah, bh, acc[t], 0, 0, 0);
      acc[t] = __builtin_amdgcn_mfma_f32_16x16x32_bf16(ah, bl, acc[t], 0, 0, 0);
      acc[t] = __builtin_amdgcn_mfma_f32_16x16x32_bf16(al, bh, acc[t], 0, 0, 0);
    }
  }

  #pragma unroll
  for (int t = 0; t < 4; ++t){
    #pragma unroll
    for (int r = 0; r < 4; ++r){
      XPh[(size_t)(m0 + quad * 4 + r) * HC + colg[t]] = f2bf(acc[t][r]);
    }
  }

  float as[4], ad[4];
  #pragma unroll
  for (int t = 0; t < 4; ++t){
    as[t] = att_src[colg[t]];
    ad[t] = att_dst[colg[t]];
  }
  float ps[4], pd[4];
  #pragma unroll
  for (int r = 0; r < 4; ++r){
    ps[r] = acc[0][r] * as[0] + acc[1][r] * as[1] + acc[2][r] * as[2] + acc[3][r] * as[3];
    pd[r] = acc[0][r] * ad[0] + acc[1][r] * ad[1] + acc[2][r] * ad[2] + acc[3][r] * ad[3];
  }
  #pragma unroll
  for (int msk = 1; msk < 16; msk <<= 1){
    #pragma unroll
    for (int r = 0; r < 4; ++r){
      ps[r] += __shfl_xor(ps[r], msk, 64);
      pd[r] += __shfl_xor(pd[r], msk, 64);
    }
  }
  if ((lane & 15) == 0){
    #pragma unroll
    for (int r = 0; r < 4; ++r){
      int n = m0 + quad * 4 + r;
      a_src[n * HEADS + w] = ps[r];
      a_dst[n * HEADS + w] = pd[r];
    }
  }
}

// ---- exclusive scan over deg, phase 1 ----
__global__ __launch_bounds__(256) void k_scan1(const int* __restrict__ deg,
                                               int* __restrict__ out,
                                               int* __restrict__ bsum, int N){
  __shared__ int tsum[256];
  int t = threadIdx.x;
  int base = blockIdx.x * 1024 + t * 4;
  int v[4]; int s = 0;
  #pragma unroll
  for (int k = 0; k < 4; ++k){ int i = base + k; v[k] = (i < N) ? deg[i] : 0; s += v[k]; }
  tsum[t] = s;
  __syncthreads();
  for (int off = 1; off < 256; off <<= 1){
    int x = (t >= off) ? tsum[t - off] : 0;
    __syncthreads();
    tsum[t] += x;
    __syncthreads();
  }
  int excl = tsum[t] - s;
  if (t == 255) bsum[blockIdx.x] = tsum[255];
  int run = excl;
  #pragma unroll
  for (int k = 0; k < 4; ++k){ int i = base + k; if (i < N) out[i] = run; run += v[k]; }
}

// ---- phase 2+3 merged: each wave computes its block's bsum prefix inline ----
__global__ __launch_bounds__(256) void k_scan23(int* __restrict__ rowstart,
                                                const int* __restrict__ bsum,
                                                int N, int E){
  int lane = threadIdx.x & 63;
  int partial = 0;
  for (int i = lane; i < blockIdx.x; i += 64) partial += bsum[i];
  #pragma unroll
  for (int msk = 32; msk; msk >>= 1) partial += __shfl_xor(partial, msk, 64);
  int base = blockIdx.x * 1024 + threadIdx.x * 4;
  #pragma unroll
  for (int k = 0; k < 4; ++k){ int i = base + k; if (i < N) rowstart[i] += partial; }
  if (blockIdx.x == 0 && threadIdx.x == 0) rowstart[N] = E;
}

// ---- scatter (atomic-free: uses precomputed pos) ----
__global__ void k_scatter(const int* __restrict__ srcc, const int* __restrict__ dstc,
                          const int* __restrict__ pos, const int* __restrict__ rowstart,
                          int* __restrict__ csr, int E){
  int e = blockIdx.x * 256 + threadIdx.x;
  if (e < E){
    int d = dstc[e];
    csr[rowstart[d] + pos[e]] = srcc[e];
  }
}

// ---- fused softmax-coef + gather: wave = node (all 4 heads) ----
__global__ __launch_bounds__(256) void k_fused(const unsigned short* __restrict__ XPh,
    const float* __restrict__ a_src, const float* __restrict__ a_dst,
    const int* __restrict__ rowstart, const int* __restrict__ csr,
    const float* __restrict__ bias, float* __restrict__ out, int N){
  __shared__ float sh[4][64][4];               // [wave][slot][head]
  int w = threadIdx.x >> 6, lane = threadIdx.x & 63;
  int n = blockIdx.x * 4 + w;
  bool alive = (n < N);
  if (!alive) n = 0;
  int r0 = rowstart[n], r1 = rowstart[n + 1];
  int deg = r1 - r0;
  int total = deg + 1;                         // + self loop (in-register)
  int h = lane >> 4;
  float4 ad4 = *(const float4*)&a_dst[n * HEADS];
  bool fast = (total <= 64);
  int jv = n;
  float msel = 0.f, inv_sel = 0.f;

  if (fast){
    if (lane < deg) jv = csr[r0 + lane];
    float l0 = -1e30f, l1 = -1e30f, l2 = -1e30f, l3 = -1e30f;
    if (lane < total){
      float4 a4 = *(const float4*)&a_src[jv * HEADS];
      l0 = a4.x + ad4.x; l0 = (l0 > 0.f) ? l0 : NEG * l0;
      l1 = a4.y + ad4.y; l1 = (l1 > 0.f) ? l1 : NEG * l1;
      l2 = a4.z + ad4.z; l2 = (l2 > 0.f) ? l2 : NEG * l2;
      l3 = a4.w + ad4.w; l3 = (l3 > 0.f) ? l3 : NEG * l3;
    }
    // no max-subtraction: logits are O(10), exp safe in fp32; inactive lanes -> exp(-1e30)=0
    float p0 = __expf(l0), p1 = __expf(l1), p2 = __expf(l2), p3 = __expf(l3);
    float s0 = p0, s1 = p1, s2 = p2, s3 = p3;
    #pragma unroll
    for (int msk = 32; msk; msk >>= 1){
      s0 += __shfl_xor(s0, msk, 64);
      s1 += __shfl_xor(s1, msk, 64);
      s2 += __shfl_xor(s2, msk, 64);
      s3 += __shfl_xor(s3, msk, 64);
    }
    if (lane < total){
      sh[w][lane][0] = p0 / s0;
      sh[w][lane][1] = p1 / s1;
      sh[w][lane][2] = p2 / s2;
      sh[w][lane][3] = p3 / s3;
    }
  } else {
    float m[4] = {-1e30f, -1e30f, -1e30f, -1e30f};
    float s[4] = {0.f, 0.f, 0.f, 0.f};
    float adArr[4] = {ad4.x, ad4.y, ad4.z, ad4.w};
    for (int e = lane; e < total; e += 64){
      int j = (e < deg) ? csr[r0 + e] : n;
      float4 a4 = *(const float4*)&a_src[j * HEADS];
      float aa[4] = {a4.x, a4.y, a4.z, a4.w};
      #pragma unroll
      for (int hh = 0; hh < 4; ++hh){
        float l = aa[hh] + adArr[hh];
        l = (l > 0.f) ? l : NEG * l;
        if (l > m[hh]){ s[hh] = s[hh] * __expf(m[hh] - l) + 1.f; m[hh] = l; }
        else            s[hh] += __expf(l - m[hh]);
      }
    }
    #pragma unroll
    for (int hh = 0; hh < 4; ++hh){
      float mm = m[hh], ss = s[hh];
      #pragma unroll
      for (int msk = 32; msk; msk >>= 1){
        float m2 = __shfl_xor(mm, msk, 64);
        float s2 = __shfl_xor(ss, msk, 64);
        float M = fmaxf(mm, m2);
        float ns = 0.f;
        if (mm > -1e29f) ns += ss * __expf(mm - M);
        if (m2 > -1e29f) ns += s2 * __expf(m2 - M);
        mm = M; ss = ns;
      }
      m[hh] = mm; s[hh] = ss;
    }
    msel    = (h == 0) ? m[0] : (h == 1) ? m[1] : (h == 2) ? m[2] : m[3];
    inv_sel = 1.f / ((h == 0) ? s[0] : (h == 1) ? s[1] : (h == 2) ? s[2] : s[3]);
  }

  __syncthreads();

  float a0 = 0.f, a1 = 0.f, a2 = 0.f, a3 = 0.f;
  const unsigned short* xb = XPh + lane * 4;
  if (fast){
    int e = 0;
    for (; e + 8 <= total; e += 8){
      int jj[8]; float cf[8]; ushort4 xv[8];
      #pragma unroll
      for (int q = 0; q < 8; ++q){
        jj[q] = __builtin_amdgcn_readlane(jv, e + q);
        cf[q] = sh[w][e + q][h];
      }
      #pragma unroll
      for (int q = 0; q < 8; ++q) xv[q] = *(const ushort4*)(xb + (size_t)jj[q] * HC);
      #pragma unroll
      for (int q = 0; q < 8; ++q){
        a0 += cf[q] * bf2f(xv[q].x); a1 += cf[q] * bf2f(xv[q].y);
        a2 += cf[q] * bf2f(xv[q].z); a3 += cf[q] * bf2f(xv[q].w);
      }
    }
    for (; e < total; ++e){
      int j = __builtin_amdgcn_readlane(jv, e);
      float c = sh[w][e][h];
      ushort4 xv = *(const ushort4*)(xb + (size_t)j * HC);
      a0 += c * bf2f(xv.x); a1 += c * bf2f(xv.y); a2 += c * bf2f(xv.z); a3 += c * bf2f(xv.w);
    }
  } else {
    float adh = (h == 0) ? ad4.x : (h == 1) ? ad4.y : (h == 2) ? ad4.z : ad4.w;
    for (int e = 0; e < total; ++e){
      int j = (e < deg) ? csr[r0 + e] : n;
      float4 a4 = *(const float4*)&a_src[j * HEADS];
      float ah = (h == 0) ? a4.x : (h == 1) ? a4.y : (h == 2) ? a4.z : a4.w;
      float l = ah + adh;
      l = (l > 0.f) ? l : NEG * l;
      float c = __expf(l - msel) * inv_sel;
      ushort4 xv = *(const ushort4*)(xb + (size_t)j * HC);
      a0 += c * bf2f(xv.x); a1 += c * bf2f(xv.y); a2 += c * bf2f(xv.z); a3 += c * bf2f(xv.w);
    }
  }
  if (alive){
    float4 b4 = *(const float4*)&bias[lane * 4];
    float4 r; r.x = a0 + b4.x; r.y = a1 + b4.y; r.z = a2 + b4.z; r.w = a3 + b4.w;
    *(float4*)&out[(size_t)n * HC + lane * 4] = r;
  }
}

extern "C" void kernel_launch(void* const* d_in, const int* in_sizes, int n_in,
                              void* d_out, int out_size, void* d_ws, size_t ws_size,
                              hipStream_t stream){
  const float* x       = (const float*)d_in[0];
  const float* W       = (const float*)d_in[1];
  const float* att_src = (const float*)d_in[2];
  const float* att_dst = (const float*)d_in[3];
  const float* bias    = (const float*)d_in[4];
  const int*   ei      = (const int*)d_in[5];
  int N = in_sizes[0] / INC;     // 50000
  int E = in_sizes[5] / 2;       // 800000

  char* p = (char*)d_ws;
  auto alloc = [&](size_t bytes)->char*{
    char* r = p; p += (bytes + 255) & ~(size_t)255; return r;
  };
  unsigned short* Wthi = (unsigned short*)alloc((size_t)INC * HC * 2);
  unsigned short* Wtlo = (unsigned short*)alloc((size_t)INC * HC * 2);
  unsigned short* XPh  = (unsigned short*)alloc((size_t)N * HC * 2);
  float* aSrc          = (float*)alloc((size_t)N * HEADS * 4);
  float* aDst          = (float*)alloc((size_t)N * HEADS * 4);
  int* deg             = (int*)alloc((size_t)N * 4);
  int* rowstart        = (int*)alloc(((size_t)N + 1) * 4);
  int* srcc            = (int*)alloc((size_t)E * 4);
  int* dstc            = (int*)alloc((size_t)E * 4);
  int* pos             = (int*)alloc((size_t)E * 4);
  int* csr             = (int*)alloc((size_t)E * 4);
  int* bsum            = (int*)alloc(256 * 4);

  hipMemsetAsync(deg, 0, (size_t)N * 4, stream);
  k_conv_e_hist<<<(E + 255) / 256, 256, 0, stream>>>(ei, srcc, dstc, pos, deg, E);

  k_split_w<<<(INC * HC) / 256, 256, 0, stream>>>(W, Wthi, Wtlo);
  k_gemm_fused<<<N / 16, 256, 0, stream>>>(x, Wthi, Wtlo, att_src, att_dst,
                                           XPh, aSrc, aDst);

  int nb = (N + 1023) / 1024;
  k_scan1<<<nb, 256, 0, stream>>>(deg, rowstart, bsum, N);
  k_scan23<<<nb, 256, 0, stream>>>(rowstart, bsum, N, E);
  k_scatter<<<(E + 255) / 256, 256, 0, stream>>>(srcc, dstc, pos, rowstart, csr, E);

  k_fused<<<(N + 3) / 4, 256, 0, stream>>>(XPh, aSrc, aDst, rowstart, csr, bias,
                                           (float*)d_out, N);
}

// Round 8
// 250.177 us; speedup vs baseline: 2.0022x; 1.0920x over previous
//
#include <hip/hip_runtime.h>

#define HEADS 4
#define OUTC 64
#define INC 128
#define HC 256   // HEADS*OUTC
#define NEG 0.2f

typedef __attribute__((ext_vector_type(8))) short bf16x8;
typedef __attribute__((ext_vector_type(4))) float f32x4;

static __device__ __forceinline__ float bf2f(unsigned short u){
  unsigned int x = ((unsigned int)u) << 16;
  return __uint_as_float(x);
}
static __device__ __forceinline__ unsigned short f2bf(float f){
  unsigned int x = __float_as_uint(f);
  unsigned int lsb = (x >> 16) & 1u;
  x += 0x7fffu + lsb;           // RNE
  return (unsigned short)(x >> 16);
}
static __device__ __forceinline__ void split8(float4 a, float4 b, bf16x8& hi, bf16x8& lo){
  float v[8] = {a.x, a.y, a.z, a.w, b.x, b.y, b.z, b.w};
  #pragma unroll
  for (int i = 0; i < 8; ++i){
    unsigned short h = f2bf(v[i]);
    hi[i] = (short)h;
    lo[i] = (short)f2bf(v[i] - bf2f(h));
  }
}

// ---- edge canonicalize (per-wave int64/int32 detection) + degree histogram ----
__global__ void k_conv_e_hist(const int* __restrict__ ei,
                              int* __restrict__ srcc, int* __restrict__ dstc,
                              int* __restrict__ pos, int* __restrict__ deg, int E){
  int e = blockIdx.x * 256 + threadIdx.x;
  bool valid = (e < E);
  int ee = valid ? e : 0;
  int hiw = ei[2 * ee + 1];
  bool hz = valid ? (hiw == 0) : true;
  unsigned long long mask = __ballot(hz);
  bool i64 = (mask == ~0ULL);
  int s, d;
  if (i64){ s = ei[2 * ee]; d = ei[2 * (size_t)E + 2 * ee]; }
  else    { s = ei[ee];     d = ei[(size_t)E + ee]; }
  if (valid){
    srcc[e] = s; dstc[e] = d;
    pos[e] = atomicAdd(&deg[d], 1);
  }
}

// ---- split + transpose W into bf16 hi/lo ----
__global__ void k_split_w(const float* __restrict__ W, unsigned short* __restrict__ Wthi,
                          unsigned short* __restrict__ Wtlo){
  int t = blockIdx.x * 256 + threadIdx.x;        // 0..32767
  int k = t >> 8, n = t & 255;
  float v = W[t];
  unsigned short hi = f2bf(v);
  Wthi[n * INC + k] = hi;
  Wtlo[n * INC + k] = f2bf(v - bf2f(hi));
}

// ---- fused GEMM + attention logits: block = 64 rows x 256 cols ----
// Wave w = head w: 4 row-tiles x 4 col-tiles of 16x16. Batched loads per kk.
__global__ __launch_bounds__(256) void k_gemm_fused(const float* __restrict__ X,
    const unsigned short* __restrict__ Wthi, const unsigned short* __restrict__ Wtlo,
    const float* __restrict__ att_src, const float* __restrict__ att_dst,
    unsigned short* __restrict__ XPh, float* __restrict__ a_src, float* __restrict__ a_dst,
    int N){
  int w = threadIdx.x >> 6, lane = threadIdx.x & 63;
  int m0 = blockIdx.x * 64;
  int quad = lane >> 4;
  int l15 = lane & 15;
  int colg[4];
  #pragma unroll
  for (int t = 0; t < 4; ++t) colg[t] = w * 64 + t * 16 + l15;

  bool rv[4]; int rowr[4];
  #pragma unroll
  for (int rt = 0; rt < 4; ++rt){
    rv[rt] = (m0 + rt * 16) < N;                 // N%16==0 -> tile all-valid or all-out
    rowr[rt] = rv[rt] ? (m0 + rt * 16 + l15) : 0;
  }

  f32x4 acc[4][4];                               // [rt][t]
  #pragma unroll
  for (int rt = 0; rt < 4; ++rt)
    #pragma unroll
    for (int t = 0; t < 4; ++t) acc[rt][t] = (f32x4){0.f, 0.f, 0.f, 0.f};

  #pragma unroll
  for (int kk = 0; kk < 4; ++kk){
    // batch-issue all independent loads for this k-step
    float4 va[4], vb[4];
    #pragma unroll
    for (int rt = 0; rt < 4; ++rt){
      const float* xr = X + (size_t)rowr[rt] * INC + kk * 32 + quad * 8;
      va[rt] = *(const float4*)xr;
      vb[rt] = *(const float4*)(xr + 4);
    }
    bf16x8 bh[4], bl[4];
    #pragma unroll
    for (int t = 0; t < 4; ++t){
      size_t bo = (size_t)colg[t] * INC + kk * 32 + quad * 8;
      bh[t] = *(const bf16x8*)(Wthi + bo);
      bl[t] = *(const bf16x8*)(Wtlo + bo);
    }
    bf16x8 ah[4], al[4];
    #pragma unroll
    for (int rt = 0; rt < 4; ++rt) split8(va[rt], vb[rt], ah[rt], al[rt]);
    #pragma unroll
    for (int rt = 0; rt < 4; ++rt){
      #pragma unroll
      for (int t = 0; t < 4; ++t){
        acc[rt][t] = __builtin_amdgcn_mfma_f32_16x16x32_bf16(ah[rt], bh[t], acc[rt][t], 0, 0, 0);
        acc[rt][t] = __builtin_amdgcn_mfma_f32_16x16x32_bf16(ah[rt], bl[t], acc[rt][t], 0, 0, 0);
        acc[rt][t] = __builtin_amdgcn_mfma_f32_16x16x32_bf16(al[rt], bh[t], acc[rt][t], 0, 0, 0);
      }
    }
  }

  // store XPh (bf16). C/D layout: col=l15, row=quad*4+r
  #pragma unroll
  for (int rt = 0; rt < 4; ++rt){
    if (!rv[rt]) continue;
    #pragma unroll
    for (int t = 0; t < 4; ++t){
      #pragma unroll
      for (int r = 0; r < 4; ++r){
        XPh[(size_t)(m0 + rt * 16 + quad * 4 + r) * HC + colg[t]] = f2bf(acc[rt][t][r]);
      }
    }
  }

  // epilogue: head-w logits for the 64 rows
  float as[4], ad[4];
  #pragma unroll
  for (int t = 0; t < 4; ++t){
    as[t] = att_src[colg[t]];
    ad[t] = att_dst[colg[t]];
  }
  #pragma unroll
  for (int rt = 0; rt < 4; ++rt){
    if (!rv[rt]) continue;
    float ps[4], pd[4];
    #pragma unroll
    for (int r = 0; r < 4; ++r){
      ps[r] = acc[rt][0][r] * as[0] + acc[rt][1][r] * as[1]
            + acc[rt][2][r] * as[2] + acc[rt][3][r] * as[3];
      pd[r] = acc[rt][0][r] * ad[0] + acc[rt][1][r] * ad[1]
            + acc[rt][2][r] * ad[2] + acc[rt][3][r] * ad[3];
    }
    #pragma unroll
    for (int msk = 1; msk < 16; msk <<= 1){
      #pragma unroll
      for (int r = 0; r < 4; ++r){
        ps[r] += __shfl_xor(ps[r], msk, 64);
        pd[r] += __shfl_xor(pd[r], msk, 64);
      }
    }
    if (l15 == 0){
      #pragma unroll
      for (int r = 0; r < 4; ++r){
        int n = m0 + rt * 16 + quad * 4 + r;
        a_src[n * HEADS + w] = ps[r];
        a_dst[n * HEADS + w] = pd[r];
      }
    }
  }
}

// ---- exclusive scan over deg, phase 1 ----
__global__ __launch_bounds__(256) void k_scan1(const int* __restrict__ deg,
                                               int* __restrict__ out,
                                               int* __restrict__ bsum, int N){
  __shared__ int tsum[256];
  int t = threadIdx.x;
  int base = blockIdx.x * 1024 + t * 4;
  int v[4]; int s = 0;
  #pragma unroll
  for (int k = 0; k < 4; ++k){ int i = base + k; v[k] = (i < N) ? deg[i] : 0; s += v[k]; }
  tsum[t] = s;
  __syncthreads();
  for (int off = 1; off < 256; off <<= 1){
    int x = (t >= off) ? tsum[t - off] : 0;
    __syncthreads();
    tsum[t] += x;
    __syncthreads();
  }
  int excl = tsum[t] - s;
  if (t == 255) bsum[blockIdx.x] = tsum[255];
  int run = excl;
  #pragma unroll
  for (int k = 0; k < 4; ++k){ int i = base + k; if (i < N) out[i] = run; run += v[k]; }
}

// ---- phase 2+3 merged ----
__global__ __launch_bounds__(256) void k_scan23(int* __restrict__ rowstart,
                                                const int* __restrict__ bsum,
                                                int N, int E){
  int lane = threadIdx.x & 63;
  int partial = 0;
  for (int i = lane; i < blockIdx.x; i += 64) partial += bsum[i];
  #pragma unroll
  for (int msk = 32; msk; msk >>= 1) partial += __shfl_xor(partial, msk, 64);
  int base = blockIdx.x * 1024 + threadIdx.x * 4;
  #pragma unroll
  for (int k = 0; k < 4; ++k){ int i = base + k; if (i < N) rowstart[i] += partial; }
  if (blockIdx.x == 0 && threadIdx.x == 0) rowstart[N] = E;
}

// ---- scatter (atomic-free) ----
__global__ void k_scatter(const int* __restrict__ srcc, const int* __restrict__ dstc,
                          const int* __restrict__ pos, const int* __restrict__ rowstart,
                          int* __restrict__ csr, int E){
  int e = blockIdx.x * 256 + threadIdx.x;
  if (e < E){
    int d = dstc[e];
    csr[rowstart[d] + pos[e]] = srcc[e];
  }
}

// ---- fused softmax-coef + gather: wave = node (all 4 heads) ----
__global__ __launch_bounds__(256) void k_fused(const unsigned short* __restrict__ XPh,
    const float* __restrict__ a_src, const float* __restrict__ a_dst,
    const int* __restrict__ rowstart, const int* __restrict__ csr,
    const float* __restrict__ bias, float* __restrict__ out, int N){
  __shared__ float sh[4][64][4];               // [wave][slot][head]
  int w = threadIdx.x >> 6, lane = threadIdx.x & 63;
  int n = blockIdx.x * 4 + w;
  bool alive = (n < N);
  if (!alive) n = 0;
  int r0 = rowstart[n], r1 = rowstart[n + 1];
  int deg = r1 - r0;
  int total = deg + 1;
  int h = lane >> 4;
  float4 ad4 = *(const float4*)&a_dst[n * HEADS];
  bool fast = (total <= 64);
  int jv = n;
  float msel = 0.f, inv_sel = 0.f;

  if (fast){
    if (lane < deg) jv = csr[r0 + lane];
    float l0 = -1e30f, l1 = -1e30f, l2 = -1e30f, l3 = -1e30f;
    if (lane < total){
      float4 a4 = *(const float4*)&a_src[jv * HEADS];
      l0 = a4.x + ad4.x; l0 = (l0 > 0.f) ? l0 : NEG * l0;
      l1 = a4.y + ad4.y; l1 = (l1 > 0.f) ? l1 : NEG * l1;
      l2 = a4.z + ad4.z; l2 = (l2 > 0.f) ? l2 : NEG * l2;
      l3 = a4.w + ad4.w; l3 = (l3 > 0.f) ? l3 : NEG * l3;
    }
    float p0 = __expf(l0), p1 = __expf(l1), p2 = __expf(l2), p3 = __expf(l3);
    float s0 = p0, s1 = p1, s2 = p2, s3 = p3;
    #pragma unroll
    for (int msk = 32; msk; msk >>= 1){
      s0 += __shfl_xor(s0, msk, 64);
      s1 += __shfl_xor(s1, msk, 64);
      s2 += __shfl_xor(s2, msk, 64);
      s3 += __shfl_xor(s3, msk, 64);
    }
    if (lane < total){
      sh[w][lane][0] = p0 / s0;
      sh[w][lane][1] = p1 / s1;
      sh[w][lane][2] = p2 / s2;
      sh[w][lane][3] = p3 / s3;
    }
  } else {
    float m[4] = {-1e30f, -1e30f, -1e30f, -1e30f};
    float s[4] = {0.f, 0.f, 0.f, 0.f};
    float adArr[4] = {ad4.x, ad4.y, ad4.z, ad4.w};
    for (int e = lane; e < total; e += 64){
      int j = (e < deg) ? csr[r0 + e] : n;
      float4 a4 = *(const float4*)&a_src[j * HEADS];
      float aa[4] = {a4.x, a4.y, a4.z, a4.w};
      #pragma unroll
      for (int hh = 0; hh < 4; ++hh){
        float l = aa[hh] + adArr[hh];
        l = (l > 0.f) ? l : NEG * l;
        if (l > m[hh]){ s[hh] = s[hh] * __expf(m[hh] - l) + 1.f; m[hh] = l; }
        else            s[hh] += __expf(l - m[hh]);
      }
    }
    #pragma unroll
    for (int hh = 0; hh < 4; ++hh){
      float mm = m[hh], ss = s[hh];
      #pragma unroll
      for (int msk = 32; msk; msk >>= 1){
        float m2 = __shfl_xor(mm, msk, 64);
        float s2 = __shfl_xor(ss, msk, 64);
        float M = fmaxf(mm, m2);
        float ns = 0.f;
        if (mm > -1e29f) ns += ss * __expf(mm - M);
        if (m2 > -1e29f) ns += s2 * __expf(m2 - M);
        mm = M; ss = ns;
      }
      m[hh] = mm; s[hh] = ss;
    }
    msel    = (h == 0) ? m[0] : (h == 1) ? m[1] : (h == 2) ? m[2] : m[3];
    inv_sel = 1.f / ((h == 0) ? s[0] : (h == 1) ? s[1] : (h == 2) ? s[2] : s[3]);
  }

  __syncthreads();

  float a0 = 0.f, a1 = 0.f, a2 = 0.f, a3 = 0.f;
  const unsigned short* xb = XPh + lane * 4;
  if (fast){
    int e = 0;
    for (; e + 8 <= total; e += 8){
      int jj[8]; float cf[8]; ushort4 xv[8];
      #pragma unroll
      for (int q = 0; q < 8; ++q){
        jj[q] = __builtin_amdgcn_readlane(jv, e + q);
        cf[q] = sh[w][e + q][h];
      }
      #pragma unroll
      for (int q = 0; q < 8; ++q) xv[q] = *(const ushort4*)(xb + (size_t)jj[q] * HC);
      #pragma unroll
      for (int q = 0; q < 8; ++q){
        a0 += cf[q] * bf2f(xv[q].x); a1 += cf[q] * bf2f(xv[q].y);
        a2 += cf[q] * bf2f(xv[q].z); a3 += cf[q] * bf2f(xv[q].w);
      }
    }
    for (; e < total; ++e){
      int j = __builtin_amdgcn_readlane(jv, e);
      float c = sh[w][e][h];
      ushort4 xv = *(const ushort4*)(xb + (size_t)j * HC);
      a0 += c * bf2f(xv.x); a1 += c * bf2f(xv.y); a2 += c * bf2f(xv.z); a3 += c * bf2f(xv.w);
    }
  } else {
    float adh = (h == 0) ? ad4.x : (h == 1) ? ad4.y : (h == 2) ? ad4.z : ad4.w;
    for (int e = 0; e < total; ++e){
      int j = (e < deg) ? csr[r0 + e] : n;
      float4 a4 = *(const float4*)&a_src[j * HEADS];
      float ah = (h == 0) ? a4.x : (h == 1) ? a4.y : (h == 2) ? a4.z : a4.w;
      float l = ah + adh;
      l = (l > 0.f) ? l : NEG * l;
      float c = __expf(l - msel) * inv_sel;
      ushort4 xv = *(const ushort4*)(xb + (size_t)j * HC);
      a0 += c * bf2f(xv.x); a1 += c * bf2f(xv.y); a2 += c * bf2f(xv.z); a3 += c * bf2f(xv.w);
    }
  }
  if (alive){
    float4 b4 = *(const float4*)&bias[lane * 4];
    float4 r; r.x = a0 + b4.x; r.y = a1 + b4.y; r.z = a2 + b4.z; r.w = a3 + b4.w;
    *(float4*)&out[(size_t)n * HC + lane * 4] = r;
  }
}

extern "C" void kernel_launch(void* const* d_in, const int* in_sizes, int n_in,
                              void* d_out, int out_size, void* d_ws, size_t ws_size,
                              hipStream_t stream){
  const float* x       = (const float*)d_in[0];
  const float* W       = (const float*)d_in[1];
  const float* att_src = (const float*)d_in[2];
  const float* att_dst = (const float*)d_in[3];
  const float* bias    = (const float*)d_in[4];
  const int*   ei      = (const int*)d_in[5];
  int N = in_sizes[0] / INC;     // 50000
  int E = in_sizes[5] / 2;       // 800000

  char* p = (char*)d_ws;
  auto alloc = [&](size_t bytes)->char*{
    char* r = p; p += (bytes + 255) & ~(size_t)255; return r;
  };
  unsigned short* Wthi = (unsigned short*)alloc((size_t)INC * HC * 2);
  unsigned short* Wtlo = (unsigned short*)alloc((size_t)INC * HC * 2);
  unsigned short* XPh  = (unsigned short*)alloc((size_t)N * HC * 2);
  float* aSrc          = (float*)alloc((size_t)N * HEADS * 4);
  float* aDst          = (float*)alloc((size_t)N * HEADS * 4);
  int* deg             = (int*)alloc((size_t)N * 4);
  int* rowstart        = (int*)alloc(((size_t)N + 1) * 4);
  int* srcc            = (int*)alloc((size_t)E * 4);
  int* dstc            = (int*)alloc((size_t)E * 4);
  int* pos             = (int*)alloc((size_t)E * 4);
  int* csr             = (int*)alloc((size_t)E * 4);
  int* bsum            = (int*)alloc(256 * 4);

  hipMemsetAsync(deg, 0, (size_t)N * 4, stream);
  k_conv_e_hist<<<(E + 255) / 256, 256, 0, stream>>>(ei, srcc, dstc, pos, deg, E);

  k_split_w<<<(INC * HC) / 256, 256, 0, stream>>>(W, Wthi, Wtlo);
  k_gemm_fused<<<(N + 63) / 64, 256, 0, stream>>>(x, Wthi, Wtlo, att_src, att_dst,
                                                  XPh, aSrc, aDst, N);

  int nb = (N + 1023) / 1024;
  k_scan1<<<nb, 256, 0, stream>>>(deg, rowstart, bsum, N);
  k_scan23<<<nb, 256, 0, stream>>>(rowstart, bsum, N, E);
  k_scatter<<<(E + 255) / 256, 256, 0, stream>>>(srcc, dstc, pos, rowstart, csr, E);

  k_fused<<<(N + 3) / 4, 256, 0, stream>>>(XPh, aSrc, aDst, rowstart, csr, bias,
                                           (float*)d_out, N);
}